// Round 13
// baseline (242.652 us; speedup 1.0000x reference)
//
#include <hip/hip_runtime.h>
#include <math.h>

#define EPS_LN 1e-5f
#define TPTS 32768
#define BT 512        // 8 waves = 2/SIMD; 64 groups of 8 lanes; 256 points/block (P=4)
#define NBLK 128      // TPTS / 256 points -> co-resident (<=256 CUs, 1 block/CU)

// d_ws layout (bytes):
//   0    : barrier counter (zeroed by hipMemsetAsync)
//   256  : per-block min/max partials (2*NBLK uints)
//   2560 : final encoded {min,max} keys
//   4096 : table (TPTS floats)
constexpr int WS_CNT  = 0;
constexpr int WS_PART = 64;
constexpr int WS_MMF  = 640;
constexpr size_t WS_TABLE_OFF = 4096;

struct Params {
  const float *W0,*b0,*W1,*b1,*W2,*b2,*W3,*b3,*W4,*b4,*W5,*b5,*W6,*b6;
  const float *g0,*be0,*g1,*be1,*g2,*be2,*g3,*be3,*g4,*be4,*g5,*be5;
};

// ---------- LDS layout (unit-interleave is conflict-free, no padding) ----------
constexpr int O_W0 = 0;      constexpr int O_B0 = 16;
constexpr int O_W1 = 32;     constexpr int O_B1 = 544;
constexpr int O_W2 = 576;    constexpr int O_B2 = 2624;
constexpr int O_W3 = 2688;   constexpr int O_B3 = 10880;
constexpr int O_W4 = 11008;  constexpr int O_B4 = 19200;
constexpr int O_W5 = 19264;  constexpr int O_B5 = 21312;
constexpr int O_W6 = 21344;  constexpr int O_B6 = 21376;
constexpr int O_G0 = 21380;  constexpr int O_BE0 = 21396;
constexpr int O_G1 = 21412;  constexpr int O_BE1 = 21444;
constexpr int O_G2 = 21476;  constexpr int O_BE2 = 21540;
constexpr int O_G3 = 21604;  constexpr int O_BE3 = 21732;
constexpr int O_G4 = 21860;  constexpr int O_BE4 = 21924;
constexpr int O_G5 = 21988;  constexpr int O_BE5 = 22020;
constexpr int SMEM_FLOATS = 22052;  // 88,208 B -> 1 block/CU (8 waves = 2/SIMD)

// ---------- order-preserving float<->uint ----------
__device__ __forceinline__ unsigned enc_f(float f) {
  unsigned u = __float_as_uint(f);
  return (u & 0x80000000u) ? ~u : (u | 0x80000000u);
}
__device__ __forceinline__ float dec_f(unsigned k) {
  unsigned u = (k & 0x80000000u) ? (k ^ 0x80000000u) : ~k;
  return __uint_as_float(u);
}

// ---------- staging ----------
__device__ __forceinline__ void stage(float* sm, int off, const float* __restrict__ src,
                                      int n, int t) {
  for (int i = t; i < n; i += BT) sm[off + i] = src[i];
}
// Unit-interleaved W staging: dest float4-unit d = c*8 + r of row i holds
// source unit r*NC + c. Read side: lane r, chunk c reads unit c*8+r -> the
// 8 lanes of a group span exactly 128B -> conflict-free; groups broadcast.
template<int IN, int OUT>
__device__ __forceinline__ void stage_wP(float* sm, int off, const float* __restrict__ src,
                                         int t) {
  constexpr int U = OUT / 4, NC = OUT / 32;
  for (int u = t; u < IN * U; u += BT) {
    int i = u / U, d = u - i * U;        // U is pow2
    int c = d >> 3, rr = d & 7;
    int s = rr * NC + c;
    *reinterpret_cast<float4*>(sm + off + i * OUT + d * 4) =
        *reinterpret_cast<const float4*>(src + i * OUT + s * 4);
  }
}

__device__ __forceinline__ void stage_all(float* sm, const Params& P, int t) {
  stage(sm, O_W0, P.W0, 16, t);         stage(sm, O_B0, P.b0, 16, t);
  stage_wP<16, 32>(sm, O_W1, P.W1, t);  stage(sm, O_B1, P.b1, 32, t);
  stage_wP<32, 64>(sm, O_W2, P.W2, t);  stage(sm, O_B2, P.b2, 64, t);
  stage_wP<64, 128>(sm, O_W3, P.W3, t); stage(sm, O_B3, P.b3, 128, t);
  stage_wP<128, 64>(sm, O_W4, P.W4, t); stage(sm, O_B4, P.b4, 64, t);
  stage_wP<64, 32>(sm, O_W5, P.W5, t);  stage(sm, O_B5, P.b5, 32, t);
  stage(sm, O_W6, P.W6, 32, t);         stage(sm, O_B6, P.b6, 1, t);
  stage(sm, O_G0, P.g0, 16, t);         stage(sm, O_BE0, P.be0, 16, t);
  stage(sm, O_G1, P.g1, 32, t);         stage(sm, O_BE1, P.be1, 32, t);
  stage(sm, O_G2, P.g2, 64, t);         stage(sm, O_BE2, P.be2, 64, t);
  stage(sm, O_G3, P.g3, 128, t);        stage(sm, O_BE3, P.be3, 128, t);
  stage(sm, O_G4, P.g4, 64, t);         stage(sm, O_BE4, P.be4, 64, t);
  stage(sm, O_G5, P.g5, 32, t);         stage(sm, O_BE5, P.be5, 32, t);
}

// ---------- 8-lane-group x 4-point building blocks (r12-proven) ----------
__device__ __forceinline__ float gred8(float v) {
  v += __shfl_xor(v, 1);
  v += __shfl_xor(v, 2);
  v += __shfl_xor(v, 4);
  return v;
}

template<int IN, int OUT>
__device__ __forceinline__ void lin8(const float (&ain)[4][IN / 8],
                                     float (&aout)[4][OUT / 8],
                                     const float* __restrict__ Ws,
                                     const float* __restrict__ bs, int r) {
  constexpr int INP = IN / 8, OUTP = OUT / 8, NC = OUTP / 4;
  #pragma unroll
  for (int c = 0; c < NC; ++c) {
    float4 b4 = *reinterpret_cast<const float4*>(bs + r * OUTP + c * 4);
    #pragma unroll
    for (int p = 0; p < 4; ++p) {
      aout[p][c * 4 + 0] = b4.x; aout[p][c * 4 + 1] = b4.y;
      aout[p][c * 4 + 2] = b4.z; aout[p][c * 4 + 3] = b4.w;
    }
  }
  #pragma unroll
  for (int i = 0; i < IN; ++i) {
    float vb[4];
    #pragma unroll
    for (int p = 0; p < 4; ++p) vb[p] = __shfl(ain[p][i % INP], i / INP, 8);
    #pragma unroll
    for (int c = 0; c < NC; ++c) {
      float4 w = *reinterpret_cast<const float4*>(Ws + i * OUT + (c * 8 + r) * 4);
      #pragma unroll
      for (int p = 0; p < 4; ++p) {
        aout[p][c * 4 + 0] = fmaf(vb[p], w.x, aout[p][c * 4 + 0]);
        aout[p][c * 4 + 1] = fmaf(vb[p], w.y, aout[p][c * 4 + 1]);
        aout[p][c * 4 + 2] = fmaf(vb[p], w.z, aout[p][c * 4 + 2]);
        aout[p][c * 4 + 3] = fmaf(vb[p], w.w, aout[p][c * 4 + 3]);
      }
    }
  }
}

template<int D>
__device__ __forceinline__ void ln8(float (&h)[4][D / 8],
                                    const float* __restrict__ g,
                                    const float* __restrict__ be, int r) {
  constexpr int DP = D / 8;
  float m[4], sc[4];
  #pragma unroll
  for (int p = 0; p < 4; ++p) {
    float s = 0.f;
    #pragma unroll
    for (int j = 0; j < DP; ++j) s += h[p][j];
    m[p] = gred8(s) * (1.0f / (float)D);
  }
  #pragma unroll
  for (int p = 0; p < 4; ++p) {
    float vs = 0.f;
    #pragma unroll
    for (int j = 0; j < DP; ++j) { float d = h[p][j] - m[p]; vs = fmaf(d, d, vs); }
    sc[p] = rsqrtf(gred8(vs) * (1.0f / (float)D) + EPS_LN);
  }
  #pragma unroll
  for (int j = 0; j < DP; ++j) {
    float gj = g[r * DP + j], bej = be[r * DP + j];
    #pragma unroll
    for (int p = 0; p < 4; ++p) {
      float tt = (h[p][j] - m[p]) * sc[p];
      tt = fmaf(tt, gj, bej);
      h[p][j] = fmaxf(tt, 0.0f);
    }
  }
}

__device__ __forceinline__ void eval8(const float (&xp)[4], int r,
                                      const float* __restrict__ sm, float (&y)[4]) {
  float a0[4][2];
  #pragma unroll
  for (int j = 0; j < 2; ++j) {
    float w = sm[O_W0 + r * 2 + j], bb = sm[O_B0 + r * 2 + j];
    #pragma unroll
    for (int p = 0; p < 4; ++p) a0[p][j] = fmaf(xp[p], w, bb);
  }
  ln8<16>(a0, sm + O_G0, sm + O_BE0, r);
  float a1[4][4];  lin8<16, 32>(a0, a1, sm + O_W1, sm + O_B1, r);  ln8<32>(a1, sm + O_G1, sm + O_BE1, r);
  float a2[4][8];  lin8<32, 64>(a1, a2, sm + O_W2, sm + O_B2, r);  ln8<64>(a2, sm + O_G2, sm + O_BE2, r);
  float a3[4][16]; lin8<64, 128>(a2, a3, sm + O_W3, sm + O_B3, r); ln8<128>(a3, sm + O_G3, sm + O_BE3, r);
  float a4[4][8];  lin8<128, 64>(a3, a4, sm + O_W4, sm + O_B4, r); ln8<64>(a4, sm + O_G4, sm + O_BE4, r);
  float a5[4][4];  lin8<64, 32>(a4, a5, sm + O_W5, sm + O_B5, r);  ln8<32>(a5, sm + O_G5, sm + O_BE5, r);
  float4 wv = *reinterpret_cast<const float4*>(sm + O_W6 + r * 4);
  #pragma unroll
  for (int p = 0; p < 4; ++p) {
    float d = a5[p][0] * wv.x;
    d = fmaf(a5[p][1], wv.y, d);
    d = fmaf(a5[p][2], wv.z, d);
    d = fmaf(a5[p][3], wv.w, d);
    y[p] = gred8(d) + sm[O_B6];
  }
}

// ---------- identical range arithmetic in build & lookup ----------
__device__ __forceinline__ void range_from_keys(unsigned kmin, unsigned kmax,
                                                float& lo, float& step, float& istep) {
  float fmin = dec_f(kmin) - 1e-3f;
  float fmax = dec_f(kmax) + 1e-3f;
  lo = fmin;
  float span = fmax - fmin;
  step  = span * (1.0f / (float)(TPTS - 1));
  istep = (float)(TPTS - 1) / span;
}

// ---------- fused minmax + build ----------
// r12 post-mortem: 256-thread block -> 1 wave/SIMD; a lone wave serializes
// its ds_read -> bpermute -> fma chain (VALUBusy 18%). BT=512 gives 2
// waves/SIMD so one wave's DS ops overlap the other's VALU.
__global__ __launch_bounds__(BT)
__attribute__((amdgpu_waves_per_eu(2, 2)))
void fused_kernel(const float* __restrict__ x, int n,
                  unsigned* __restrict__ wsu, float* __restrict__ table,
                  Params P) {
  __shared__ float sm[SMEM_FLOATS];
  __shared__ float redmn[8], redmx[8];
  __shared__ unsigned redk[16];
  const int t = threadIdx.x;
  const int b = blockIdx.x;

  stage_all(sm, P, t);  // overlaps the minmax global reads

  // ---- phase 1: grid-stride min/max over x ----
  const int gtid = b * BT + t;
  const int gstride = NBLK * BT;
  float lmin = 3.0e38f, lmax = -3.0e38f;
  for (int i = gtid * 4; i + 3 < n; i += gstride * 4) {
    float4 v = *reinterpret_cast<const float4*>(x + i);
    lmin = fminf(lmin, fminf(fminf(v.x, v.y), fminf(v.z, v.w)));
    lmax = fmaxf(lmax, fmaxf(fmaxf(v.x, v.y), fmaxf(v.z, v.w)));
  }
  if (gtid == 0) {
    for (int i = n & ~3; i < n; ++i) { lmin = fminf(lmin, x[i]); lmax = fmaxf(lmax, x[i]); }
  }
  #pragma unroll
  for (int off = 32; off > 0; off >>= 1) {
    lmin = fminf(lmin, __shfl_xor(lmin, off));
    lmax = fmaxf(lmax, __shfl_xor(lmax, off));
  }
  if ((t & 63) == 0) { redmn[t >> 6] = lmin; redmx[t >> 6] = lmax; }
  __syncthreads();  // also orders LDS staging before the build phase

  // ---- grid barrier ----
  if (t == 0) {
    float bmin = redmn[0], bmax = redmx[0];
    #pragma unroll
    for (int w = 1; w < 8; ++w) { bmin = fminf(bmin, redmn[w]); bmax = fmaxf(bmax, redmx[w]); }
    __hip_atomic_store(&wsu[WS_PART + 2 * b],     enc_f(bmin),
                       __ATOMIC_RELEASE, __HIP_MEMORY_SCOPE_AGENT);
    __hip_atomic_store(&wsu[WS_PART + 2 * b + 1], enc_f(bmax),
                       __ATOMIC_RELEASE, __HIP_MEMORY_SCOPE_AGENT);
    __hip_atomic_fetch_add(&wsu[WS_CNT], 1u, __ATOMIC_ACQ_REL, __HIP_MEMORY_SCOPE_AGENT);
    while (__hip_atomic_load(&wsu[WS_CNT], __ATOMIC_ACQUIRE, __HIP_MEMORY_SCOPE_AGENT) < NBLK)
      __builtin_amdgcn_s_sleep(8);
  }
  __syncthreads();

  // ---- reduce the NBLK partial pairs (threads 0..NBLK-1 = waves 0,1) ----
  {
    unsigned kmin = 0xFFFFFFFFu, kmax = 0u;
    if (t < NBLK) {
      kmin = __hip_atomic_load(&wsu[WS_PART + 2 * t], __ATOMIC_RELAXED,
                               __HIP_MEMORY_SCOPE_AGENT);
      kmax = __hip_atomic_load(&wsu[WS_PART + 2 * t + 1], __ATOMIC_RELAXED,
                               __HIP_MEMORY_SCOPE_AGENT);
    }
    #pragma unroll
    for (int off = 32; off > 0; off >>= 1) {
      kmin = min(kmin, (unsigned)__shfl_xor((int)kmin, off));
      kmax = max(kmax, (unsigned)__shfl_xor((int)kmax, off));
    }
    if ((t & 63) == 0 && t < NBLK) { redk[t >> 6] = kmin; redk[8 + (t >> 6)] = kmax; }
  }
  __syncthreads();
  unsigned ukmin = min(redk[0], redk[1]);
  unsigned ukmax = max(redk[8], redk[9]);
  if (b == 0 && t == 0) { wsu[WS_MMF] = ukmin; wsu[WS_MMF + 1] = ukmax; }

  // ---- phase 2: build 256 points/block, 4 per 8-lane group slot ----
  float lo, step, istep;
  range_from_keys(ukmin, ukmax, lo, step, istep);
  const int r = t & 7;
  const int base = b * 256 + (t >> 3) * 4;
  float xp[4], y[4];
  #pragma unroll
  for (int p = 0; p < 4; ++p) xp[p] = fmaf((float)(base + p), step, lo);
  eval8(xp, r, sm, y);
  if (r == 0)
    *reinterpret_cast<float4*>(table + base) = make_float4(y[0], y[1], y[2], y[3]);
}

// ---------- lookup: plain global gather, max occupancy ----------
// Table = 128 KB, fully L2-resident. No LDS (r12's LDS staging capped
// occupancy at 1 block/CU for no total-time gain). 1024 blocks -> plenty of
// waves to hide the divergent-gather latency. If lookup is the ~107us
// residual, this form will surface it in top-5 with honest counters.
__device__ __forceinline__ float interp(float xv, float lo, float istep,
                                        const float* __restrict__ tb) {
  float tt = (xv - lo) * istep;
  tt = fminf(fmaxf(tt, 0.0f), (float)(TPTS - 1));
  int i = (int)tt;
  if (i > TPTS - 2) i = TPTS - 2;
  float f = tt - (float)i;
  float t0 = tb[i], t1 = tb[i + 1];
  return fmaf(f, t1 - t0, t0);
}

__global__ __launch_bounds__(256) void lookup_kernel(const float* __restrict__ x,
                                                     const float* __restrict__ table,
                                                     const unsigned* __restrict__ wsu,
                                                     float* __restrict__ out, int n) {
  float lo, step, istep;
  range_from_keys(wsu[WS_MMF], wsu[WS_MMF + 1], lo, step, istep);
  int tid = blockIdx.x * blockDim.x + threadIdx.x;
  int stride = gridDim.x * blockDim.x;
  for (int i = tid * 4; i + 3 < n; i += stride * 4) {
    float4 v = *reinterpret_cast<const float4*>(x + i);
    float4 rr;
    rr.x = interp(v.x, lo, istep, table);
    rr.y = interp(v.y, lo, istep, table);
    rr.z = interp(v.z, lo, istep, table);
    rr.w = interp(v.w, lo, istep, table);
    *reinterpret_cast<float4*>(out + i) = rr;
  }
  if (tid == 0) {
    for (int i = n & ~3; i < n; ++i) out[i] = interp(x[i], lo, istep, table);
  }
}

// Fallback (ws too small): direct evaluation with the same eval8 path.
__global__ __launch_bounds__(BT)
__attribute__((amdgpu_waves_per_eu(2, 2)))
void direct_kernel(const float* __restrict__ x, float* __restrict__ out, int n,
                   Params P) {
  __shared__ float sm[SMEM_FLOATS];
  const int t = threadIdx.x;
  stage_all(sm, P, t);
  __syncthreads();
  const int r = t & 7;
  const int gstride = gridDim.x * (BT / 8) * 4;
  for (int base = (blockIdx.x * (BT / 8) + (t >> 3)) * 4; base < n; base += gstride) {
    float xp[4], y[4];
    #pragma unroll
    for (int p = 0; p < 4; ++p) xp[p] = (base + p < n) ? x[base + p] : 0.0f;
    eval8(xp, r, sm, y);
    if (r == 0) {
      #pragma unroll
      for (int p = 0; p < 4; ++p) if (base + p < n) out[base + p] = y[p];
    }
  }
}

extern "C" void kernel_launch(void* const* d_in, const int* in_sizes, int n_in,
                              void* d_out, int out_size, void* d_ws, size_t ws_size,
                              hipStream_t stream) {
  const float* x = (const float*)d_in[0];
  Params P;
  P.W0 = (const float*)d_in[1];  P.b0 = (const float*)d_in[2];
  P.W1 = (const float*)d_in[3];  P.b1 = (const float*)d_in[4];
  P.W2 = (const float*)d_in[5];  P.b2 = (const float*)d_in[6];
  P.W3 = (const float*)d_in[7];  P.b3 = (const float*)d_in[8];
  P.W4 = (const float*)d_in[9];  P.b4 = (const float*)d_in[10];
  P.W5 = (const float*)d_in[11]; P.b5 = (const float*)d_in[12];
  P.W6 = (const float*)d_in[13]; P.b6 = (const float*)d_in[14];
  P.g0 = (const float*)d_in[15]; P.be0 = (const float*)d_in[16];
  P.g1 = (const float*)d_in[17]; P.be1 = (const float*)d_in[18];
  P.g2 = (const float*)d_in[19]; P.be2 = (const float*)d_in[20];
  P.g3 = (const float*)d_in[21]; P.be3 = (const float*)d_in[22];
  P.g4 = (const float*)d_in[23]; P.be4 = (const float*)d_in[24];
  P.g5 = (const float*)d_in[25]; P.be5 = (const float*)d_in[26];

  int n = in_sizes[0];
  float* out = (float*)d_out;

  if (ws_size < WS_TABLE_OFF + (size_t)TPTS * sizeof(float)) {
    direct_kernel<<<256, BT, 0, stream>>>(x, out, n, P);
    return;
  }

  unsigned* wsu = (unsigned*)d_ws;
  float* table = (float*)((char*)d_ws + WS_TABLE_OFF);

  hipMemsetAsync(d_ws, 0, 64, stream);  // zero the barrier counter
  fused_kernel<<<NBLK, BT, 0, stream>>>(x, n, wsu, table, P);
  lookup_kernel<<<1024, 256, 0, stream>>>(x, table, wsu, out, n);
}